// Round 2
// baseline (143.056 us; speedup 1.0000x reference)
//
#include <hip/hip_runtime.h>

// JPEG-compression-as-augmentation, collapsed to luma-only per-channel codec.
// Chroma planes of a gray (v,v,v) image are exactly 128 and the chroma codec
// is an exact fixed point, so only the Y path survives. Per (B,C) channel:
//   min/max normalize -> *255 -> edge-pad 14x14 -> 16x16 -> 4 blocks of 8x8
//   R = C^T * diffround( C*(X-128)*C^T / (Y_T*f) ) * (Y_T*f) * C + 128
//   out = clip(R,0,255)/255 * rng + min        (f = 0.02 at quality 99)
//
// Round-6 changes vs round-5 (passed, absmax 1.56e-2, dur 81.4; kernel ~37us
// vs <10us pipe models -> latency/fence-bound, not issue-bound):
//  * REGISTER TRANSPOSES: the 8x8 inter-pass transposes are now 3-stage
//    __shfl_xor butterflies within each 8-lane group (pure exact data
//    movement, bit-identical results). Deletes ALL FOUR lgkmcnt(0) full
//    drains between passes, the block-storage LDS traffic, and both 9.2 KB
//    ping-pong buffers.
//  * 2-DEEP PERSISTENT PIPELINE: grid 2048, each block owns 2 chunks of 8
//    channels. Both chunks' global_load_lds DMAs issue back-to-back before a
//    SINGLE vmcnt(0): the cold HBM stall is paid once per block (not once
//    per grid round), chunk-1 data is resident long before chunk-0 compute
//    ends, and the grid fits in one dispatch round (no 2nd cold start).
//  * LDS = raw double buffer only (2 x 6272 B = 12.5 KB, was 18.4 KB); the
//    output plane reuses the current chunk's raw region (dead after pass 1;
//    same-wave DS ops complete in order). Fences: 1 vmcnt + 1 lgkm drain per
//    chunk, vs 1+6 per chunk before.
// Retained: barrier-free per-wave ownership, global_load_lds width-16
// staging, transposed prescaled quant table (2 float4/lane), stride-14
// plane scatter (row-groups 16 banks apart, channels offset 4 -> worst
// 2-way = free), EXACT fp32 quant divide (round-boundary sensitive - do
// not trade ulps), float4 global I/O, __launch_bounds__(256,8).

namespace {

constexpr int CH_PER_WG = 8;       // 4 waves * 2 channels
constexpr int HW        = 196;     // 14*14
constexpr int CPW       = 2 * HW;  // floats per wave per chunk (2 channels)
constexpr int CHUNK_F   = CH_PER_WG * HW;  // 1568 floats per chunk per block

// Orthonormal 8-point DCT-II matrix: CM[u][x] = 0.5*alpha_u*cos((2x+1)u*pi/16).
constexpr float CM[8][8] = {
  { 0.35355339059327376f,  0.35355339059327376f,  0.35355339059327376f,  0.35355339059327376f,
    0.35355339059327376f,  0.35355339059327376f,  0.35355339059327376f,  0.35355339059327376f},
  { 0.49039264020161522f,  0.41573480615127262f,  0.27778511650980114f,  0.09754516100806417f,
   -0.09754516100806417f, -0.27778511650980114f, -0.41573480615127262f, -0.49039264020161522f},
  { 0.46193976625564337f,  0.19134171618254492f, -0.19134171618254492f, -0.46193976625564337f,
   -0.46193976625564337f, -0.19134171618254492f,  0.19134171618254492f,  0.46193976625564337f},
  { 0.41573480615127262f, -0.09754516100806417f, -0.49039264020161522f, -0.27778511650980114f,
    0.27778511650980114f,  0.49039264020161522f,  0.09754516100806417f, -0.41573480615127262f},
  { 0.35355339059327376f, -0.35355339059327376f, -0.35355339059327376f,  0.35355339059327376f,
    0.35355339059327376f, -0.35355339059327376f, -0.35355339059327376f,  0.35355339059327376f},
  { 0.27778511650980114f, -0.49039264020161522f,  0.09754516100806417f,  0.41573480615127262f,
   -0.41573480615127262f, -0.09754516100806417f,  0.49039264020161522f, -0.27778511650980114f},
  { 0.19134171618254492f, -0.46193976625564337f,  0.46193976625564337f, -0.19134171618254492f,
   -0.19134171618254492f,  0.46193976625564337f, -0.46193976625564337f,  0.19134171618254492f},
  { 0.09754516100806417f, -0.27778511650980114f,  0.41573480615127262f, -0.49039264020161522f,
    0.49039264020161522f, -0.41573480615127262f,  0.27778511650980114f, -0.09754516100806417f},
};

} // namespace

// Transposed, pre-scaled luma quant table: QVT[i][k] = Y_T[k][i] * 0.02f.
// int*0.02f is constant-folded in IEEE fp32 RN -> bit-identical to the
// runtime v_mul of earlier rounds. Row i is 16B-aligned: one lane reads its
// whole column as two float4 while the staging DMA is in flight.
#define SF 0.02f
__device__ __align__(16) const float QVT[8][8] = {
  {16*SF, 12*SF, 14*SF, 14*SF, 18*SF,  24*SF,  49*SF,  72*SF},
  {11*SF, 12*SF, 13*SF, 17*SF, 22*SF,  35*SF,  64*SF,  92*SF},
  {10*SF, 14*SF, 16*SF, 22*SF, 37*SF,  55*SF,  78*SF,  95*SF},
  {16*SF, 19*SF, 24*SF, 29*SF, 56*SF,  64*SF,  87*SF,  98*SF},
  {24*SF, 26*SF, 40*SF, 51*SF, 68*SF,  81*SF, 103*SF, 112*SF},
  {40*SF, 58*SF, 57*SF, 87*SF, 109*SF, 104*SF, 121*SF, 100*SF},
  {51*SF, 60*SF, 69*SF, 80*SF, 103*SF, 113*SF, 120*SF, 103*SF},
  {61*SF, 55*SF, 56*SF, 62*SF, 77*SF,  92*SF, 101*SF,  99*SF},
};
#undef SF

// Intra-wave fences. All producers and consumers of any LDS/VMEM data are in
// the same wave, so no s_barrier exists anywhere in the kernel.
#define WAVE_LDS_SYNC() asm volatile("s_waitcnt lgkmcnt(0)" ::: "memory")
#define WAVE_VM_SYNC()  asm volatile("s_waitcnt vmcnt(0)" ::: "memory")

typedef __attribute__((address_space(1))) const void gvoid_t;
typedef __attribute__((address_space(3))) void       lvoid_t;

// Exact 8x8 transpose across an 8-lane group: element at (reg r, lane l)
// moves to (reg l, lane r). Stage d swaps bit d between reg and lane index
// where they differ; after d=1,2,4 the indices are exchanged. Pure data
// movement -> bit-identical to the LDS round-trip it replaces. Masks <= 4
// stay inside the 8-lane group.
__device__ __forceinline__ void xpose8(float x[8], int lane8) {
  #pragma unroll
  for (int d = 1; d < 8; d <<= 1) {
    const bool up = (lane8 & d) == 0;
    #pragma unroll
    for (int r0 = 0; r0 < 8; ++r0) {
      if ((r0 & d) == 0) {
        const int r1 = r0 | d;
        float send = up ? x[r1] : x[r0];
        float got  = __shfl_xor(send, d, 64);
        if (up) x[r1] = got; else x[r0] = got;
      }
    }
  }
}

__global__ __launch_bounds__(256, 8)
void jpeg_codec_kernel(const float* __restrict__ x, float* __restrict__ out) {
  // Double-buffered raw staging; the output plane reuses the current chunk's
  // buffer (raw is dead after pass 1). 12544 B/block -> thread-limited
  // occupancy: 8 blocks/CU, 100 KB LDS/CU.
  __shared__ __align__(16) float s_raw[2][4 * CPW];

  const int tid = threadIdx.x;
  const int w   = tid >> 6;       // wave 0..3
  const int wl  = tid & 63;       // lane in wave
  const int chl = (tid >> 5) & 1; // channel-in-wave 0/1
  const int l   = tid & 31;       // lane-in-channel
  const int b   = l >> 3;         // block 0..3
  const int i   = l & 7;          // row/col 0..7

  const long long c0 = 2LL * blockIdx.x;  // first of this block's two chunks

  // ---- 1. issue BOTH chunks' staging DMA back-to-back ----
  // global_load_lds writes lane j's 16B to (uniform lds base) + j*16 — the
  // contiguous layout we want. 2 vmem ops per chunk per wave.
  #pragma unroll
  for (int p = 0; p < 2; ++p) {
    const float4* x4 = (const float4*)x + (c0 + p) * (CHUNK_F / 4) + w * (CPW / 4);
    float* raw = &s_raw[p][w * CPW];
    __builtin_amdgcn_global_load_lds((gvoid_t*)(x4 + wl), (lvoid_t*)raw, 16, 0, 0);
    if (wl < CPW / 4 - 64)  // lanes 0..33 stage f4 64..97
      __builtin_amdgcn_global_load_lds((gvoid_t*)(x4 + 64 + wl),
                                       (lvoid_t*)(raw + 256), 16, 0, 0);
  }

  // per-lane quant column, loaded while the DMAs are in flight
  float qv8[8];
  {
    const float4* qt = (const float4*)QVT[i];
    float4 qa = qt[0], qb = qt[1];
    qv8[0] = qa.x; qv8[1] = qa.y; qv8[2] = qa.z; qv8[3] = qa.w;
    qv8[4] = qb.x; qv8[5] = qb.y; qv8[6] = qb.z; qv8[7] = qb.w;
  }

  // Single cold stall per block: both chunks were issued together and arrive
  // back-to-back, so draining to 0 costs barely more than waiting chunk 0,
  // and is robust against the compiler interleaving its own vmem loads.
  WAVE_VM_SYNC();

  #pragma unroll
  for (int p = 0; p < 2; ++p) {
    float* rawp = &s_raw[p][w * CPW];
    const float* raw_ch = rawp + chl * HW;  // this lane's channel raw

    // ---- 2. per-channel min/max: float4 reads + shuffle butterfly ----
    float mn, inv, scale;        // uniform within the 32-lane channel group
    {
      float vmin = 1e30f, vmax = -1e30f;
      const float4* c4 = (const float4*)raw_ch;     // offsets %16 == 0
      {
        float4 v = c4[l];                           // f4 0..31
        vmin = fminf(fminf(vmin, v.x), fminf(v.y, fminf(v.z, v.w)));
        vmax = fmaxf(fmaxf(vmax, v.x), fmaxf(v.y, fmaxf(v.z, v.w)));
      }
      if (l < 17) {                                 // f4 32..48
        float4 v = c4[l + 32];
        vmin = fminf(fminf(vmin, v.x), fminf(v.y, fminf(v.z, v.w)));
        vmax = fmaxf(fmaxf(vmax, v.x), fmaxf(v.y, fmaxf(v.z, v.w)));
      }
      #pragma unroll
      for (int off = 16; off; off >>= 1) {          // xor<=16 stays in 32-group
        vmin = fminf(vmin, __shfl_xor(vmin, off, 64));
        vmax = fmaxf(vmax, __shfl_xor(vmax, off, 64));
      }
      mn = vmin;
      float rng = vmax - vmin + 1e-5f;
      inv   = 255.0f / rng;                         // the only normalize divide
      scale = rng * (1.0f / 255.0f);
    }

    // ---- 3. four separable passes chained through register transposes ----
    float m[8];

    // pass 1: lane (b,i) reads padded row pr's 8 cols from raw, normalizes,
    // computes m[k] = (C * Xrow)[k]  -> lane holds column i of Y = C*X^T.
    {
      const int pr = ((b >> 1) << 3) + i;          // padded row 0..15
      int sr = pr - 1; sr = sr < 0 ? 0 : (sr > 13 ? 13 : sr);
      const float* rp = raw_ch + sr * 14;
      float t[8];
      #pragma unroll
      for (int j = 0; j < 8; ++j) {
        int pc = ((b & 1) << 3) + j - 1; pc = pc < 0 ? 0 : (pc > 13 ? 13 : pc);
        t[j] = fmaf(rp[pc] - mn, inv, -128.0f);
      }
      #pragma unroll
      for (int k = 0; k < 8; ++k) {
        float s = 0.0f;
        #pragma unroll
        for (int j = 0; j < 8; ++j) s = fmaf(t[j], CM[k][j], s);
        m[k] = s;
      }
    }
    xpose8(m, i);     // lane now holds row i of Y

    // pass 2: s[k] = D[k][i], D = C*X*C^T; fused quantization.
    // s/qv stays an EXACT division: it feeds rintf; round-boundary flips
    // cost up to ~0.08 absmax each — don't trade ulps here.
    float q[8];
    #pragma unroll
    for (int k = 0; k < 8; ++k) {
      float s = 0.0f;
      #pragma unroll
      for (int j = 0; j < 8; ++j) s = fmaf(m[j], CM[k][j], s);
      float qv = qv8[k];                           // tab * factor, fp32
      float xq = s / qv;
      float r  = rintf(xq);                        // round half to even
      float e  = xq - r;
      q[k] = (r + e * e * e) * qv;                 // lane holds column i of Qs
    }
    xpose8(q, i);     // lane now holds row i of Qs

    // pass 3: t3[k] = (Qs*C)[i][k]
    float t3[8];
    #pragma unroll
    for (int k = 0; k < 8; ++k) {
      float s = 0.0f;
      #pragma unroll
      for (int j = 0; j < 8; ++j) s = fmaf(q[j], CM[j][k], s);
      t3[k] = s;
    }
    xpose8(t3, i);    // lane now holds (Qs*C)[j][i] over j

    // pass 4: s[k] = R[k][i], R = C^T*Qs*C. Fuse crop(1:-1) + (+128) + clip
    // + un-normalize and scatter into a natural 14x14 plane over this
    // chunk's raw region (dead after pass 1; same-wave DS ops are processed
    // in order, so the earlier raw reads complete first). Per-k write banks
    // distinct, row-groups 16 banks apart, channels offset 4 -> <=2-way.
    {
      const int pc    = ((b & 1) << 3) + i;        // padded col 0..15
      const int prb   = (b >> 1) << 3;             // padded row base 0 or 8
      const bool pcv  = (pc >= 1) && (pc <= 14);
      const int obase = prb * 14 + pc - 15;        // (pr-1)*14 + (pc-1) at k=0
      float* crop = rawp + chl * HW;
      #pragma unroll
      for (int k = 0; k < 8; ++k) {
        float s = 0.0f;
        #pragma unroll
        for (int j = 0; j < 8; ++j) s = fmaf(t3[j], CM[j][k], s);
        const int pr = prb + k;
        if (pcv && pr >= 1 && pr <= 14) {
          float v = fminf(fmaxf(s + 128.0f, 0.0f), 255.0f);
          crop[obase + 14 * k] = fmaf(v, scale, mn);
        }
      }
    }
    WAVE_LDS_SYNC();   // plane writes land before the cross-lane copy reads

    // ---- 4. pure vectorized copy: LDS plane -> global (coalesced f4) ----
    {
      const float4* src = (const float4*)rawp;
      float4* o4 = (float4*)out + (c0 + p) * (CHUNK_F / 4) + w * (CPW / 4);
      o4[wl] = src[wl];                            // f4 0..63
      if (wl < CPW / 4 - 64)                       // lanes 0..33: f4 64..97
        o4[64 + wl] = src[64 + wl];
    }
  }
}

extern "C" void kernel_launch(void* const* d_in, const int* in_sizes, int n_in,
                              void* d_out, int out_size, void* d_ws, size_t ws_size,
                              hipStream_t stream) {
  const float* x = (const float*)d_in[0];
  float* out     = (float*)d_out;
  const int ntot   = in_sizes[0];                   // 32*1024*14*14
  const int nch    = ntot / HW;                     // 32768 channels
  const int chunks = (nch + CH_PER_WG - 1) / CH_PER_WG;  // 4096
  const int grid   = (chunks + 1) / 2;              // 2048 blocks, 2 chunks each
  hipLaunchKernelGGL(jpeg_codec_kernel, dim3(grid), dim3(256), 0, stream,
                     x, out);
}

// Round 4
// 141.498 us; speedup vs baseline: 1.0110x; 1.0110x over previous
//
#include <hip/hip_runtime.h>

// JPEG-compression-as-augmentation, collapsed to luma-only per-channel codec.
// Chroma planes of a gray (v,v,v) image are exactly 128 and the chroma codec
// is an exact fixed point, so only the Y path survives. Per (B,C) channel:
//   min/max normalize -> *255 -> edge-pad 14x14 -> 16x16 -> 4 blocks of 8x8
//   R = C^T * diffround( C*(X-128)*C^T / (Y_T*f) ) * (Y_T*f) * C + 128
//   out = clip(R,0,255)/255 * rng + min        (f = 0.02 at quality 99)
//
// Round-8: EXACT round-6 body (which PASSED, absmax 1.56e-2) with ONE change:
//   __launch_bounds__(256,8) -> (256,4).
// Attribution history:
//  * round-6 (lb(256,8), full unroll): CORRECT but spilled — allocator
//    squeezed the ~55-90 reg working set into 32 VGPRs; scratch round-trips
//    showed as WRITE_SIZE 147MB / FETCH 49MB vs 26MB ideal, kernel 80us.
//  * round-7 (lb(256,4) + "#pragma unroll 1" chunk loop): WRONG RESULTS
//    (absmax 11). Dataflow is provably race-free (all sync intra-wave,
//    per-wave disjoint regions), so the non-unrolled codegen path
//    (runtime LDS bases + inline-asm fences inside a back-edge) is the
//    suspect miscompile trigger. DO NOT reintroduce "#pragma unroll 1" here.
//  * round-8 isolates the variable: round-6 code, 128-VGPR budget (4
//    waves/EU). Working set fits -> no spill, and correctness attribution
//    is clean either way.
// Retained round-6 structure:
//  * register __shfl_xor transposes between passes (no inter-pass LDS, no
//    lgkmcnt drains, bit-identical data movement).
//  * 2-deep pipeline: both chunks' global_load_lds DMAs issued before ONE
//    vmcnt(0); grid 2048 blocks x 2 chunks, single dispatch round.
//  * LDS = raw double buffer only (12.5 KB); output plane reuses the dead
//    raw region; 1 vmcnt + 1 lgkm drain per chunk, no s_barrier anywhere.
//  * transposed prescaled quant table (2 float4/lane), EXACT fp32 quant
//    divide (round-boundary sensitive - do not trade ulps), float4 I/O.

namespace {

constexpr int CH_PER_WG = 8;       // 4 waves * 2 channels
constexpr int HW        = 196;     // 14*14
constexpr int CPW       = 2 * HW;  // floats per wave per chunk (2 channels)
constexpr int CHUNK_F   = CH_PER_WG * HW;  // 1568 floats per chunk per block

// Orthonormal 8-point DCT-II matrix: CM[u][x] = 0.5*alpha_u*cos((2x+1)u*pi/16).
constexpr float CM[8][8] = {
  { 0.35355339059327376f,  0.35355339059327376f,  0.35355339059327376f,  0.35355339059327376f,
    0.35355339059327376f,  0.35355339059327376f,  0.35355339059327376f,  0.35355339059327376f},
  { 0.49039264020161522f,  0.41573480615127262f,  0.27778511650980114f,  0.09754516100806417f,
   -0.09754516100806417f, -0.27778511650980114f, -0.41573480615127262f, -0.49039264020161522f},
  { 0.46193976625564337f,  0.19134171618254492f, -0.19134171618254492f, -0.46193976625564337f,
   -0.46193976625564337f, -0.19134171618254492f,  0.19134171618254492f,  0.46193976625564337f},
  { 0.41573480615127262f, -0.09754516100806417f, -0.49039264020161522f, -0.27778511650980114f,
    0.27778511650980114f,  0.49039264020161522f,  0.09754516100806417f, -0.41573480615127262f},
  { 0.35355339059327376f, -0.35355339059327376f, -0.35355339059327376f,  0.35355339059327376f,
    0.35355339059327376f, -0.35355339059327376f, -0.35355339059327376f,  0.35355339059327376f},
  { 0.27778511650980114f, -0.49039264020161522f,  0.09754516100806417f,  0.41573480615127262f,
   -0.41573480615127262f, -0.09754516100806417f,  0.49039264020161522f, -0.27778511650980114f},
  { 0.19134171618254492f, -0.46193976625564337f,  0.46193976625564337f, -0.19134171618254492f,
   -0.19134171618254492f,  0.46193976625564337f, -0.46193976625564337f,  0.19134171618254492f},
  { 0.09754516100806417f, -0.27778511650980114f,  0.41573480615127262f, -0.49039264020161522f,
    0.49039264020161522f, -0.41573480615127262f,  0.27778511650980114f, -0.09754516100806417f},
};

} // namespace

// Transposed, pre-scaled luma quant table: QVT[i][k] = Y_T[k][i] * 0.02f.
// int*0.02f is constant-folded in IEEE fp32 RN -> bit-identical to the
// runtime v_mul of earlier rounds. Row i is 16B-aligned: one lane reads its
// whole column as two float4 while the staging DMA is in flight.
#define SF 0.02f
__device__ __align__(16) const float QVT[8][8] = {
  {16*SF, 12*SF, 14*SF, 14*SF, 18*SF,  24*SF,  49*SF,  72*SF},
  {11*SF, 12*SF, 13*SF, 17*SF, 22*SF,  35*SF,  64*SF,  92*SF},
  {10*SF, 14*SF, 16*SF, 22*SF, 37*SF,  55*SF,  78*SF,  95*SF},
  {16*SF, 19*SF, 24*SF, 29*SF, 56*SF,  64*SF,  87*SF,  98*SF},
  {24*SF, 26*SF, 40*SF, 51*SF, 68*SF,  81*SF, 103*SF, 112*SF},
  {40*SF, 58*SF, 57*SF, 87*SF, 109*SF, 104*SF, 121*SF, 100*SF},
  {51*SF, 60*SF, 69*SF, 80*SF, 103*SF, 113*SF, 120*SF, 103*SF},
  {61*SF, 55*SF, 56*SF, 62*SF, 77*SF,  92*SF, 101*SF,  99*SF},
};
#undef SF

// Intra-wave fences. All producers and consumers of any LDS/VMEM data are in
// the same wave, so no s_barrier exists anywhere in the kernel.
#define WAVE_LDS_SYNC() asm volatile("s_waitcnt lgkmcnt(0)" ::: "memory")
#define WAVE_VM_SYNC()  asm volatile("s_waitcnt vmcnt(0)" ::: "memory")

typedef __attribute__((address_space(1))) const void gvoid_t;
typedef __attribute__((address_space(3))) void       lvoid_t;

// Exact 8x8 transpose across an 8-lane group: element at (reg r, lane l)
// moves to (reg l, lane r). Stage d swaps bit d between reg and lane index
// where they differ; after d=1,2,4 the indices are exchanged. Pure data
// movement -> bit-identical to the LDS round-trip it replaces. Masks <= 4
// stay inside the 8-lane group.
__device__ __forceinline__ void xpose8(float x[8], int lane8) {
  #pragma unroll
  for (int d = 1; d < 8; d <<= 1) {
    const bool up = (lane8 & d) == 0;
    #pragma unroll
    for (int r0 = 0; r0 < 8; ++r0) {
      if ((r0 & d) == 0) {
        const int r1 = r0 | d;
        float send = up ? x[r1] : x[r0];
        float got  = __shfl_xor(send, d, 64);
        if (up) x[r1] = got; else x[r0] = got;
      }
    }
  }
}

__global__ __launch_bounds__(256, 4)
void jpeg_codec_kernel(const float* __restrict__ x, float* __restrict__ out) {
  // Double-buffered raw staging; the output plane reuses the current chunk's
  // buffer (raw is dead after pass 1). 12544 B/block.
  __shared__ __align__(16) float s_raw[2][4 * CPW];

  const int tid = threadIdx.x;
  const int w   = tid >> 6;       // wave 0..3
  const int wl  = tid & 63;       // lane in wave
  const int chl = (tid >> 5) & 1; // channel-in-wave 0/1
  const int l   = tid & 31;       // lane-in-channel
  const int b   = l >> 3;         // block 0..3
  const int i   = l & 7;          // row/col 0..7

  const long long c0 = 2LL * blockIdx.x;  // first of this block's two chunks

  // ---- 1. issue BOTH chunks' staging DMA back-to-back ----
  // global_load_lds writes lane j's 16B to (uniform lds base) + j*16 — the
  // contiguous layout we want. 2 vmem ops per chunk per wave.
  #pragma unroll
  for (int p = 0; p < 2; ++p) {
    const float4* x4 = (const float4*)x + (c0 + p) * (CHUNK_F / 4) + w * (CPW / 4);
    float* raw = &s_raw[p][w * CPW];
    __builtin_amdgcn_global_load_lds((gvoid_t*)(x4 + wl), (lvoid_t*)raw, 16, 0, 0);
    if (wl < CPW / 4 - 64)  // lanes 0..33 stage f4 64..97
      __builtin_amdgcn_global_load_lds((gvoid_t*)(x4 + 64 + wl),
                                       (lvoid_t*)(raw + 256), 16, 0, 0);
  }

  // per-lane quant column, loaded while the DMAs are in flight
  float qv8[8];
  {
    const float4* qt = (const float4*)QVT[i];
    float4 qa = qt[0], qb = qt[1];
    qv8[0] = qa.x; qv8[1] = qa.y; qv8[2] = qa.z; qv8[3] = qa.w;
    qv8[4] = qb.x; qv8[5] = qb.y; qv8[6] = qb.z; qv8[7] = qb.w;
  }

  // Single cold stall per block: both chunks were issued together and arrive
  // back-to-back, so draining to 0 costs barely more than waiting chunk 0,
  // and is robust against the compiler interleaving its own vmem loads.
  WAVE_VM_SYNC();

  #pragma unroll
  for (int p = 0; p < 2; ++p) {
    float* rawp = &s_raw[p][w * CPW];
    const float* raw_ch = rawp + chl * HW;  // this lane's channel raw

    // ---- 2. per-channel min/max: float4 reads + shuffle butterfly ----
    float mn, inv, scale;        // uniform within the 32-lane channel group
    {
      float vmin = 1e30f, vmax = -1e30f;
      const float4* c4 = (const float4*)raw_ch;     // offsets %16 == 0
      {
        float4 v = c4[l];                           // f4 0..31
        vmin = fminf(fminf(vmin, v.x), fminf(v.y, fminf(v.z, v.w)));
        vmax = fmaxf(fmaxf(vmax, v.x), fmaxf(v.y, fmaxf(v.z, v.w)));
      }
      if (l < 17) {                                 // f4 32..48
        float4 v = c4[l + 32];
        vmin = fminf(fminf(vmin, v.x), fminf(v.y, fminf(v.z, v.w)));
        vmax = fmaxf(fmaxf(vmax, v.x), fmaxf(v.y, fmaxf(v.z, v.w)));
      }
      #pragma unroll
      for (int off = 16; off; off >>= 1) {          // xor<=16 stays in 32-group
        vmin = fminf(vmin, __shfl_xor(vmin, off, 64));
        vmax = fmaxf(vmax, __shfl_xor(vmax, off, 64));
      }
      mn = vmin;
      float rng = vmax - vmin + 1e-5f;
      inv   = 255.0f / rng;                         // the only normalize divide
      scale = rng * (1.0f / 255.0f);
    }

    // ---- 3. four separable passes chained through register transposes ----
    float m[8];

    // pass 1: lane (b,i) reads padded row pr's 8 cols from raw, normalizes,
    // computes m[k] = (C * Xrow)[k]  -> lane holds column i of Y = C*X^T.
    {
      const int pr = ((b >> 1) << 3) + i;          // padded row 0..15
      int sr = pr - 1; sr = sr < 0 ? 0 : (sr > 13 ? 13 : sr);
      const float* rp = raw_ch + sr * 14;
      float t[8];
      #pragma unroll
      for (int j = 0; j < 8; ++j) {
        int pc = ((b & 1) << 3) + j - 1; pc = pc < 0 ? 0 : (pc > 13 ? 13 : pc);
        t[j] = fmaf(rp[pc] - mn, inv, -128.0f);
      }
      #pragma unroll
      for (int k = 0; k < 8; ++k) {
        float s = 0.0f;
        #pragma unroll
        for (int j = 0; j < 8; ++j) s = fmaf(t[j], CM[k][j], s);
        m[k] = s;
      }
    }
    xpose8(m, i);     // lane now holds row i of Y

    // pass 2: s[k] = D[k][i], D = C*X*C^T; fused quantization.
    // s/qv stays an EXACT division: it feeds rintf; round-boundary flips
    // cost up to ~0.08 absmax each — don't trade ulps here.
    float q[8];
    #pragma unroll
    for (int k = 0; k < 8; ++k) {
      float s = 0.0f;
      #pragma unroll
      for (int j = 0; j < 8; ++j) s = fmaf(m[j], CM[k][j], s);
      float qv = qv8[k];                           // tab * factor, fp32
      float xq = s / qv;
      float r  = rintf(xq);                        // round half to even
      float e  = xq - r;
      q[k] = (r + e * e * e) * qv;                 // lane holds column i of Qs
    }
    xpose8(q, i);     // lane now holds row i of Qs

    // pass 3: t3[k] = (Qs*C)[i][k]
    float t3[8];
    #pragma unroll
    for (int k = 0; k < 8; ++k) {
      float s = 0.0f;
      #pragma unroll
      for (int j = 0; j < 8; ++j) s = fmaf(q[j], CM[j][k], s);
      t3[k] = s;
    }
    xpose8(t3, i);    // lane now holds (Qs*C)[j][i] over j

    // pass 4: s[k] = R[k][i], R = C^T*Qs*C. Fuse crop(1:-1) + (+128) + clip
    // + un-normalize and scatter into a natural 14x14 plane over this
    // chunk's raw region (dead after pass 1; same-wave DS ops are processed
    // in order, so the earlier raw reads complete first). Per-k write banks
    // distinct, row-groups 16 banks apart, channels offset 4 -> <=2-way.
    {
      const int pc    = ((b & 1) << 3) + i;        // padded col 0..15
      const int prb   = (b >> 1) << 3;             // padded row base 0 or 8
      const bool pcv  = (pc >= 1) && (pc <= 14);
      const int obase = prb * 14 + pc - 15;        // (pr-1)*14 + (pc-1) at k=0
      float* crop = rawp + chl * HW;
      #pragma unroll
      for (int k = 0; k < 8; ++k) {
        float s = 0.0f;
        #pragma unroll
        for (int j = 0; j < 8; ++j) s = fmaf(t3[j], CM[j][k], s);
        const int pr = prb + k;
        if (pcv && pr >= 1 && pr <= 14) {
          float v = fminf(fmaxf(s + 128.0f, 0.0f), 255.0f);
          crop[obase + 14 * k] = fmaf(v, scale, mn);
        }
      }
    }
    WAVE_LDS_SYNC();   // plane writes land before the cross-lane copy reads

    // ---- 4. pure vectorized copy: LDS plane -> global (coalesced f4) ----
    {
      const float4* src = (const float4*)rawp;
      float4* o4 = (float4*)out + (c0 + p) * (CHUNK_F / 4) + w * (CPW / 4);
      o4[wl] = src[wl];                            // f4 0..63
      if (wl < CPW / 4 - 64)                       // lanes 0..33: f4 64..97
        o4[64 + wl] = src[64 + wl];
    }
  }
}

extern "C" void kernel_launch(void* const* d_in, const int* in_sizes, int n_in,
                              void* d_out, int out_size, void* d_ws, size_t ws_size,
                              hipStream_t stream) {
  const float* x = (const float*)d_in[0];
  float* out     = (float*)d_out;
  const int ntot   = in_sizes[0];                   // 32*1024*14*14
  const int nch    = ntot / HW;                     // 32768 channels
  const int chunks = (nch + CH_PER_WG - 1) / CH_PER_WG;  // 4096
  const int grid   = (chunks + 1) / 2;              // 2048 blocks, 2 chunks each
  hipLaunchKernelGGL(jpeg_codec_kernel, dim3(grid), dim3(256), 0, stream,
                     x, out);
}

// Round 5
// 84.679 us; speedup vs baseline: 1.6894x; 1.6710x over previous
//
#include <hip/hip_runtime.h>

// JPEG-compression-as-augmentation, collapsed to luma-only per-channel codec.
// Chroma planes of a gray (v,v,v) image are exactly 128 and the chroma codec
// is an exact fixed point, so only the Y path survives. Per (B,C) channel:
//   min/max normalize -> *255 -> edge-pad 14x14 -> 16x16 -> 4 blocks of 8x8
//   R = C^T * diffround( C*(X-128)*C^T / (Y_T*f) ) * (Y_T*f) * C + 128
//   out = clip(R,0,255)/255 * rng + min        (f = 0.02 at quality 99)
//
// Round-9: NO LOCAL ARRAYS. Attribution from rounds 6-8:
//  * round-8 proved the scratch spill is NOT allocator pressure:
//    lb(256,8)->(256,4) left VGPR_Count pinned at 32 and WRITE_SIZE at
//    146MB (vs 26MB ideal). The float[8] locals (t/m/q/t3/qv8 + the array
//    passed by pointer into xpose8) were never SROA-promoted: they lived in
//    scratch at ANY register budget. Write/read asymmetry (+120MB W, +23MB
//    R) = scratch evictions vs L2-absorbed re-reads.
//  * fix: every 8-vector is 8 NAMED SCALARS; dot products are macro fmaf
//    chains with the ORIGINAL nesting order (bit-exact); CM[][] only ever
//    indexed by literals (folds to inline constants, zero memory); the
//    lane transpose is a macro over named scalars using pure selects.
//  * round-7 lesson kept: chunk loop stays FULLY UNROLLED ("#pragma unroll
//    1" produced wrong results; do not reintroduce).
// Retained structure (round-6 dataflow, proven correct in round-8):
//  * register __shfl_xor transposes between passes (no inter-pass LDS, no
//    lgkmcnt drains, bit-identical data movement).
//  * 2-deep pipeline: both chunks' global_load_lds DMAs issued before ONE
//    vmcnt(0); grid 2048 blocks x 2 chunks, single dispatch round.
//  * LDS = raw double buffer only (12.5 KB); output plane reuses the dead
//    raw region; 1 vmcnt + 1 lgkm drain per chunk, no s_barrier anywhere.
//  * transposed prescaled quant table (2 float4/lane), EXACT fp32 quant
//    divide (round-boundary sensitive - do not trade ulps), float4 I/O.

namespace {

constexpr int CH_PER_WG = 8;       // 4 waves * 2 channels
constexpr int HW        = 196;     // 14*14
constexpr int CPW       = 2 * HW;  // floats per wave per chunk (2 channels)
constexpr int CHUNK_F   = CH_PER_WG * HW;  // 1568 floats per chunk per block

// Orthonormal 8-point DCT-II matrix: CM[u][x] = 0.5*alpha_u*cos((2x+1)u*pi/16).
// Only ever indexed with compile-time literals -> folds to inline constants.
constexpr float CM[8][8] = {
  { 0.35355339059327376f,  0.35355339059327376f,  0.35355339059327376f,  0.35355339059327376f,
    0.35355339059327376f,  0.35355339059327376f,  0.35355339059327376f,  0.35355339059327376f},
  { 0.49039264020161522f,  0.41573480615127262f,  0.27778511650980114f,  0.09754516100806417f,
   -0.09754516100806417f, -0.27778511650980114f, -0.41573480615127262f, -0.49039264020161522f},
  { 0.46193976625564337f,  0.19134171618254492f, -0.19134171618254492f, -0.46193976625564337f,
   -0.46193976625564337f, -0.19134171618254492f,  0.19134171618254492f,  0.46193976625564337f},
  { 0.41573480615127262f, -0.09754516100806417f, -0.49039264020161522f, -0.27778511650980114f,
    0.27778511650980114f,  0.49039264020161522f,  0.09754516100806417f, -0.41573480615127262f},
  { 0.35355339059327376f, -0.35355339059327376f, -0.35355339059327376f,  0.35355339059327376f,
    0.35355339059327376f, -0.35355339059327376f, -0.35355339059327376f,  0.35355339059327376f},
  { 0.27778511650980114f, -0.49039264020161522f,  0.09754516100806417f,  0.41573480615127262f,
   -0.41573480615127262f, -0.09754516100806417f,  0.49039264020161522f, -0.27778511650980114f},
  { 0.19134171618254492f, -0.46193976625564337f,  0.46193976625564337f, -0.19134171618254492f,
   -0.19134171618254492f,  0.46193976625564337f, -0.46193976625564337f,  0.19134171618254492f},
  { 0.09754516100806417f, -0.27778511650980114f,  0.41573480615127262f, -0.49039264020161522f,
    0.49039264020161522f, -0.41573480615127262f,  0.27778511650980114f, -0.09754516100806417f},
};

} // namespace

// Transposed, pre-scaled luma quant table: QVT[i][k] = Y_T[k][i] * 0.02f.
// int*0.02f is constant-folded in IEEE fp32 RN -> bit-identical to the
// runtime v_mul of earlier rounds. Row i is 16B-aligned: one lane reads its
// whole column as two float4 while the staging DMA is in flight.
#define SF 0.02f
__device__ __align__(16) const float QVT[8][8] = {
  {16*SF, 12*SF, 14*SF, 14*SF, 18*SF,  24*SF,  49*SF,  72*SF},
  {11*SF, 12*SF, 13*SF, 17*SF, 22*SF,  35*SF,  64*SF,  92*SF},
  {10*SF, 14*SF, 16*SF, 22*SF, 37*SF,  55*SF,  78*SF,  95*SF},
  {16*SF, 19*SF, 24*SF, 29*SF, 56*SF,  64*SF,  87*SF,  98*SF},
  {24*SF, 26*SF, 40*SF, 51*SF, 68*SF,  81*SF, 103*SF, 112*SF},
  {40*SF, 58*SF, 57*SF, 87*SF, 109*SF, 104*SF, 121*SF, 100*SF},
  {51*SF, 60*SF, 69*SF, 80*SF, 103*SF, 113*SF, 120*SF, 103*SF},
  {61*SF, 55*SF, 56*SF, 62*SF, 77*SF,  92*SF, 101*SF,  99*SF},
};
#undef SF

// Intra-wave fences. All producers and consumers of any LDS/VMEM data are in
// the same wave, so no s_barrier exists anywhere in the kernel.
#define WAVE_LDS_SYNC() asm volatile("s_waitcnt lgkmcnt(0)" ::: "memory")
#define WAVE_VM_SYNC()  asm volatile("s_waitcnt vmcnt(0)" ::: "memory")

typedef __attribute__((address_space(1))) const void gvoid_t;
typedef __attribute__((address_space(3))) void       lvoid_t;

// Dot products as explicit fmaf chains, SAME nesting order as the original
// "s=0; for j: s=fmaf(x[j],C,s)" loop -> bit-identical results.
// ROWDOT: sum_j x_j * CM[K][j]   COLDOT: sum_j x_j * CM[j][K]
#define ROWDOT(K, x0,x1,x2,x3,x4,x5,x6,x7) \
  fmaf(x7, CM[K][7], fmaf(x6, CM[K][6], fmaf(x5, CM[K][5], fmaf(x4, CM[K][4], \
  fmaf(x3, CM[K][3], fmaf(x2, CM[K][2], fmaf(x1, CM[K][1], fmaf(x0, CM[K][0], 0.0f))))))))
#define COLDOT(K, x0,x1,x2,x3,x4,x5,x6,x7) \
  fmaf(x7, CM[7][K], fmaf(x6, CM[6][K], fmaf(x5, CM[5][K], fmaf(x4, CM[4][K], \
  fmaf(x3, CM[3][K], fmaf(x2, CM[2][K], fmaf(x1, CM[1][K], fmaf(x0, CM[0][K], 0.0f))))))))

// One butterfly step of the exact 8x8 lane-group transpose, on NAMED
// scalars (pure cndmask selects, no memory). up lane ((i&d)==0) exchanges
// its B with the partner's A. Pure data movement -> bit-identical.
#define XST(D, A, B) { float snd_ = upd_ ? (B) : (A); \
                       float got_ = __shfl_xor(snd_, (D), 64); \
                       (A) = upd_ ? (A) : got_; \
                       (B) = upd_ ? got_ : (B); }

// Full transpose: element (reg r, lane l) -> (reg l, lane r) within each
// 8-lane group. Stages d=1,2,4 as in the original xpose8.
#define XPOSE8(x0,x1,x2,x3,x4,x5,x6,x7, LANE) { \
  { const bool upd_ = ((LANE) & 1) == 0; \
    XST(1, x0, x1) XST(1, x2, x3) XST(1, x4, x5) XST(1, x6, x7) } \
  { const bool upd_ = ((LANE) & 2) == 0; \
    XST(2, x0, x2) XST(2, x1, x3) XST(2, x4, x6) XST(2, x5, x7) } \
  { const bool upd_ = ((LANE) & 4) == 0; \
    XST(4, x0, x4) XST(4, x1, x5) XST(4, x2, x6) XST(4, x3, x7) } }

__global__ __launch_bounds__(256, 4)
void jpeg_codec_kernel(const float* __restrict__ x, float* __restrict__ out) {
  // Double-buffered raw staging; the output plane reuses the current chunk's
  // buffer (raw is dead after pass 1). 12544 B/block.
  __shared__ __align__(16) float s_raw[2][4 * CPW];

  const int tid = threadIdx.x;
  const int w   = tid >> 6;       // wave 0..3
  const int wl  = tid & 63;       // lane in wave
  const int chl = (tid >> 5) & 1; // channel-in-wave 0/1
  const int l   = tid & 31;       // lane-in-channel
  const int b   = l >> 3;         // block 0..3
  const int i   = l & 7;          // row/col 0..7

  const long long c0 = 2LL * blockIdx.x;  // first of this block's two chunks

  // ---- 1. issue BOTH chunks' staging DMA back-to-back ----
  // global_load_lds writes lane j's 16B to (uniform lds base) + j*16 — the
  // contiguous layout we want. 2 vmem ops per chunk per wave.
  #pragma unroll
  for (int p = 0; p < 2; ++p) {
    const float4* x4 = (const float4*)x + (c0 + p) * (CHUNK_F / 4) + w * (CPW / 4);
    float* raw = &s_raw[p][w * CPW];
    __builtin_amdgcn_global_load_lds((gvoid_t*)(x4 + wl), (lvoid_t*)raw, 16, 0, 0);
    if (wl < CPW / 4 - 64)  // lanes 0..33 stage f4 64..97
      __builtin_amdgcn_global_load_lds((gvoid_t*)(x4 + 64 + wl),
                                       (lvoid_t*)(raw + 256), 16, 0, 0);
  }

  // per-lane quant column as NAMED scalars, loaded while DMAs are in flight
  float qv0, qv1, qv2, qv3, qv4, qv5, qv6, qv7;
  {
    const float4* qt = (const float4*)QVT[i];
    float4 qa = qt[0], qb = qt[1];
    qv0 = qa.x; qv1 = qa.y; qv2 = qa.z; qv3 = qa.w;
    qv4 = qb.x; qv5 = qb.y; qv6 = qb.z; qv7 = qb.w;
  }

  // Single cold stall per block: both chunks were issued together and arrive
  // back-to-back, so draining to 0 costs barely more than waiting chunk 0.
  WAVE_VM_SYNC();

  #pragma unroll
  for (int p = 0; p < 2; ++p) {
    float* rawp = &s_raw[p][w * CPW];
    const float* raw_ch = rawp + chl * HW;  // this lane's channel raw

    // ---- 2. per-channel min/max: float4 reads + shuffle butterfly ----
    float mn, inv, scale;        // uniform within the 32-lane channel group
    {
      float vmin = 1e30f, vmax = -1e30f;
      const float4* c4 = (const float4*)raw_ch;     // offsets %16 == 0
      {
        float4 v = c4[l];                           // f4 0..31
        vmin = fminf(fminf(vmin, v.x), fminf(v.y, fminf(v.z, v.w)));
        vmax = fmaxf(fmaxf(vmax, v.x), fmaxf(v.y, fmaxf(v.z, v.w)));
      }
      if (l < 17) {                                 // f4 32..48
        float4 v = c4[l + 32];
        vmin = fminf(fminf(vmin, v.x), fminf(v.y, fminf(v.z, v.w)));
        vmax = fmaxf(fmaxf(vmax, v.x), fmaxf(v.y, fmaxf(v.z, v.w)));
      }
      #pragma unroll
      for (int off = 16; off; off >>= 1) {          // xor<=16 stays in 32-group
        vmin = fminf(vmin, __shfl_xor(vmin, off, 64));
        vmax = fmaxf(vmax, __shfl_xor(vmax, off, 64));
      }
      mn = vmin;
      float rng = vmax - vmin + 1e-5f;
      inv   = 255.0f / rng;                         // the only normalize divide
      scale = rng * (1.0f / 255.0f);
    }

    // ---- 3. four separable passes chained through register transposes ----

    // pass 1: lane (b,i) reads padded row pr's 8 cols from raw, normalizes
    // (u0..u7), computes a_k = (C * Urow)[k] -> lane holds col i of C*X^T.
    float a0, a1, a2, a3, a4, a5, a6, a7;
    {
      const int pr = ((b >> 1) << 3) + i;          // padded row 0..15
      int sr = pr - 1; sr = sr < 0 ? 0 : (sr > 13 ? 13 : sr);
      const float* rp = raw_ch + sr * 14;
      const int cb = (b & 1) << 3;                 // padded col base 0 or 8
      float u0, u1, u2, u3, u4, u5, u6, u7;
      #define LDU(J, UJ) { int pc_ = cb + (J) - 1; \
                           pc_ = pc_ < 0 ? 0 : (pc_ > 13 ? 13 : pc_); \
                           UJ = fmaf(rp[pc_] - mn, inv, -128.0f); }
      LDU(0, u0) LDU(1, u1) LDU(2, u2) LDU(3, u3)
      LDU(4, u4) LDU(5, u5) LDU(6, u6) LDU(7, u7)
      #undef LDU
      a0 = ROWDOT(0, u0,u1,u2,u3,u4,u5,u6,u7);
      a1 = ROWDOT(1, u0,u1,u2,u3,u4,u5,u6,u7);
      a2 = ROWDOT(2, u0,u1,u2,u3,u4,u5,u6,u7);
      a3 = ROWDOT(3, u0,u1,u2,u3,u4,u5,u6,u7);
      a4 = ROWDOT(4, u0,u1,u2,u3,u4,u5,u6,u7);
      a5 = ROWDOT(5, u0,u1,u2,u3,u4,u5,u6,u7);
      a6 = ROWDOT(6, u0,u1,u2,u3,u4,u5,u6,u7);
      a7 = ROWDOT(7, u0,u1,u2,u3,u4,u5,u6,u7);
    }
    XPOSE8(a0,a1,a2,a3,a4,a5,a6,a7, i)   // lane now holds row i of Y

    // pass 2: D = C*X*C^T (lane holds column i), fused quantization.
    // s/qv stays an EXACT division: it feeds rintf; round-boundary flips
    // cost up to ~0.08 absmax each — don't trade ulps here.
    float g0, g1, g2, g3, g4, g5, g6, g7;
    #define QUANT(K, QV, DST) { \
      float s_  = ROWDOT(K, a0,a1,a2,a3,a4,a5,a6,a7); \
      float xq_ = s_ / (QV); \
      float r_  = rintf(xq_);            /* round half to even */ \
      float e_  = xq_ - r_; \
      DST = (r_ + e_ * e_ * e_) * (QV); }
    QUANT(0, qv0, g0) QUANT(1, qv1, g1) QUANT(2, qv2, g2) QUANT(3, qv3, g3)
    QUANT(4, qv4, g4) QUANT(5, qv5, g5) QUANT(6, qv6, g6) QUANT(7, qv7, g7)
    #undef QUANT
    XPOSE8(g0,g1,g2,g3,g4,g5,g6,g7, i)   // lane now holds row i of Qs

    // pass 3: h_k = (Qs*C)[i][k]
    float h0, h1, h2, h3, h4, h5, h6, h7;
    h0 = COLDOT(0, g0,g1,g2,g3,g4,g5,g6,g7);
    h1 = COLDOT(1, g0,g1,g2,g3,g4,g5,g6,g7);
    h2 = COLDOT(2, g0,g1,g2,g3,g4,g5,g6,g7);
    h3 = COLDOT(3, g0,g1,g2,g3,g4,g5,g6,g7);
    h4 = COLDOT(4, g0,g1,g2,g3,g4,g5,g6,g7);
    h5 = COLDOT(5, g0,g1,g2,g3,g4,g5,g6,g7);
    h6 = COLDOT(6, g0,g1,g2,g3,g4,g5,g6,g7);
    h7 = COLDOT(7, g0,g1,g2,g3,g4,g5,g6,g7);
    XPOSE8(h0,h1,h2,h3,h4,h5,h6,h7, i)   // lane now holds (Qs*C)[j][i] over j

    // pass 4: s_k = R[k][i], R = C^T*Qs*C. Fuse crop(1:-1) + (+128) + clip
    // + un-normalize and scatter into a natural 14x14 plane over this
    // chunk's raw region (dead after pass 1; same-wave DS ops are processed
    // in order, so the earlier raw reads complete first). Per-k write banks
    // distinct, row-groups 16 banks apart, channels offset 4 -> <=2-way.
    {
      const int pc    = ((b & 1) << 3) + i;        // padded col 0..15
      const int prb   = (b >> 1) << 3;             // padded row base 0 or 8
      const bool pcv  = (pc >= 1) && (pc <= 14);
      const int obase = prb * 14 + pc - 15;        // (pr-1)*14 + (pc-1) at k=0
      float* crop = rawp + chl * HW;
      #define OUTK(K) { \
        float s_ = COLDOT(K, h0,h1,h2,h3,h4,h5,h6,h7); \
        const int pr_ = prb + (K); \
        if (pcv && pr_ >= 1 && pr_ <= 14) { \
          float v_ = fminf(fmaxf(s_ + 128.0f, 0.0f), 255.0f); \
          crop[obase + 14 * (K)] = fmaf(v_, scale, mn); } }
      OUTK(0) OUTK(1) OUTK(2) OUTK(3) OUTK(4) OUTK(5) OUTK(6) OUTK(7)
      #undef OUTK
    }
    WAVE_LDS_SYNC();   // plane writes land before the cross-lane copy reads

    // ---- 4. pure vectorized copy: LDS plane -> global (coalesced f4) ----
    {
      const float4* src = (const float4*)rawp;
      float4* o4 = (float4*)out + (c0 + p) * (CHUNK_F / 4) + w * (CPW / 4);
      o4[wl] = src[wl];                            // f4 0..63
      if (wl < CPW / 4 - 64)                       // lanes 0..33: f4 64..97
        o4[64 + wl] = src[64 + wl];
    }
  }
}

extern "C" void kernel_launch(void* const* d_in, const int* in_sizes, int n_in,
                              void* d_out, int out_size, void* d_ws, size_t ws_size,
                              hipStream_t stream) {
  const float* x = (const float*)d_in[0];
  float* out     = (float*)d_out;
  const int ntot   = in_sizes[0];                   // 32*1024*14*14
  const int nch    = ntot / HW;                     // 32768 channels
  const int chunks = (nch + CH_PER_WG - 1) / CH_PER_WG;  // 4096
  const int grid   = (chunks + 1) / 2;              // 2048 blocks, 2 chunks each
  hipLaunchKernelGGL(jpeg_codec_kernel, dim3(grid), dim3(256), 0, stream,
                     x, out);
}